// Round 13
// baseline (860.582 us; speedup 1.0000x reference)
//
#include <hip/hip_runtime.h>
#include <hip/hip_bf16.h>
#include <cstdint>
#include <cstddef>

// ---------------------------------------------------------------------------
// EnrichAttention: B=32, L1=L2=512, H=A=256, 3H=768, 2H=512
// R19: R18 (verified 714.0us) + GRU gate-tail overlap:
//      - all 8 h B-fragments preloaded (lgkm drain front-loaded, fence gone)
//      - MFMA burst split {0,2,4} then {1,3,5}; g=0 gate branch emitted
//        between the halves so its ~150cyc trans chain overlaps the second
//        24-MFMA block (separate pipes, no dependency); g=1 gates remain
//        the only serial tail.
//      All non-GRU kernels byte-identical to R17/R18.
// ---------------------------------------------------------------------------

typedef short s8v __attribute__((ext_vector_type(8)));      // 8 bf16 (4 VGPRs)
typedef float f4v __attribute__((ext_vector_type(4)));      // MFMA accumulator
typedef _Float16 h8v __attribute__((ext_vector_type(8)));   // 8 f16 (4 VGPRs)

#if __has_builtin(__builtin_amdgcn_sched_barrier)
#define SCHED_FENCE() __builtin_amdgcn_sched_barrier(0)
#else
#define SCHED_FENCE() asm volatile("" ::: "memory")
#endif

// Workgroup barrier waiting only on LDS (lgkmcnt). Only hhf (LDS) carries
// cross-thread deps in the GRU loop; global loads stay in flight across it.
__device__ __forceinline__ void bar_lds() {
    asm volatile("s_waitcnt lgkmcnt(0)\n\ts_barrier" ::: "memory");
}

__device__ __forceinline__ float fast_exp(float x) {
#if __has_builtin(__builtin_amdgcn_exp2f)
    return __builtin_amdgcn_exp2f(x * 1.44269504f);
#else
    return __expf(x);
#endif
}
__device__ __forceinline__ float fast_rcp(float x) {
#if __has_builtin(__builtin_amdgcn_rcpf)
    return __builtin_amdgcn_rcpf(x);
#else
    return 1.f / x;
#endif
}
__device__ __forceinline__ float fast_sig(float x) { return fast_rcp(1.f + fast_exp(-x)); }
__device__ __forceinline__ float fast_tanh(float x) {
    return 1.f - 2.f * fast_rcp(1.f + fast_exp(2.f * x));
}

// Dynamic extract from f4v with compile-time vector indices only (rule #20:
// no runtime-indexed array -> no scratch; lowers to 3 v_cndmask).
__device__ __forceinline__ float sel4(f4v v, int rr) {
    float a = (rr & 1) ? v[1] : v[0];
    float b = (rr & 1) ? v[3] : v[2];
    return (rr & 2) ? b : a;
}

// ---------------------------------------------------------------------------
// MFMA bf16 NT GEMM: C[M,N] = A[M,K] * B[N,K]^T. (Verified in R5.)
// ---------------------------------------------------------------------------
__global__ __launch_bounds__(256) void gemm_bf16(
    const __hip_bfloat16* __restrict__ A, int lda, long long sA,
    const __hip_bfloat16* __restrict__ B, int ldb, long long sB,
    void* __restrict__ C, int ldc, long long sC,
    int K,
    const float* __restrict__ bias,
    const float* __restrict__ emul, int ldmul,
    int relu, int accum, int out_bf16)
{
    __shared__ short As[128][40];
    __shared__ short Bs[128][40];

    const int tid  = threadIdx.x;
    const int wave = tid >> 6, lane = tid & 63;
    const int quad = lane >> 4, l16 = lane & 15;
    const int wrow = (wave >> 1) * 64, wcol = (wave & 1) * 64;
    const int m0 = blockIdx.y * 128, n0 = blockIdx.x * 128;

    const short* Ab = (const short*)A + (size_t)blockIdx.z * sA;
    const short* Bb = (const short*)B + (size_t)blockIdx.z * sB;

    f4v acc[4][4];
#pragma unroll
    for (int i = 0; i < 4; ++i)
#pragma unroll
        for (int j = 0; j < 4; ++j) acc[i][j] = 0.f;

    const int r0 = tid >> 2,        s0 = (tid & 3) * 8;
    const int r1 = (tid + 256) >> 2, s1 = ((tid + 256) & 3) * 8;

    for (int k0 = 0; k0 < K; k0 += 32) {
        *(s8v*)&As[r0][s0] = *(const s8v*)(Ab + (size_t)(m0 + r0) * lda + k0 + s0);
        *(s8v*)&As[r1][s1] = *(const s8v*)(Ab + (size_t)(m0 + r1) * lda + k0 + s1);
        *(s8v*)&Bs[r0][s0] = *(const s8v*)(Bb + (size_t)(n0 + r0) * ldb + k0 + s0);
        *(s8v*)&Bs[r1][s1] = *(const s8v*)(Bb + (size_t)(n0 + r1) * ldb + k0 + s1);
        __syncthreads();

        s8v af[4], bf[4];
#pragma unroll
        for (int i = 0; i < 4; ++i)
            af[i] = *(const s8v*)&As[wrow + i * 16 + l16][quad * 8];
#pragma unroll
        for (int j = 0; j < 4; ++j)
            bf[j] = *(const s8v*)&Bs[wcol + j * 16 + l16][quad * 8];
#pragma unroll
        for (int i = 0; i < 4; ++i)
#pragma unroll
            for (int j = 0; j < 4; ++j)
                acc[i][j] = __builtin_amdgcn_mfma_f32_16x16x32_bf16(
                    af[i], bf[j], acc[i][j], 0, 0, 0);
        __syncthreads();
    }

    float* Cf = (float*)C + (size_t)blockIdx.z * sC;
    __hip_bfloat16* Cb = (__hip_bfloat16*)C + (size_t)blockIdx.z * sC;
#pragma unroll
    for (int i = 0; i < 4; ++i)
#pragma unroll
        for (int j = 0; j < 4; ++j)
#pragma unroll
            for (int r = 0; r < 4; ++r) {
                const int m = m0 + wrow + i * 16 + quad * 4 + r;
                const int n = n0 + wcol + j * 16 + l16;
                float v = acc[i][j][r];
                if (bias)  v += bias[n];
                if (accum) v += Cf[(size_t)m * ldc + n];
                if (emul)  v *= emul[(size_t)m * ldmul + n];
                if (relu)  v = fmaxf(v, 0.f);
                if (out_bf16) Cb[(size_t)m * ldc + n] = __float2bfloat16(v);
                else          Cf[(size_t)m * ldc + n] = v;
            }
}

// ---------------------------------------------------------------------------
// M GEMM + fused softmax numerator (verified R13):
//   E = bf16(exp((a1d@a2^T)*W)); S[b][n] += column sums (fp32 atomics).
// ---------------------------------------------------------------------------
__global__ __launch_bounds__(256) void gemm_M(
    const __hip_bfloat16* __restrict__ A,   // a1db [32][512][256]
    const __hip_bfloat16* __restrict__ B,   // a2b  [32][512][256]
    __hip_bfloat16* __restrict__ E,         // Msb  [32][512][512]
    const float* __restrict__ Wm,           // [512,512]
    float* __restrict__ S)                  // [32][512] (pre-zeroed)
{
    __shared__ short As[128][40];
    __shared__ short Bs[128][40];

    const int tid  = threadIdx.x;
    const int wave = tid >> 6, lane = tid & 63;
    const int quad = lane >> 4, l16 = lane & 15;
    const int wrow = (wave >> 1) * 64, wcol = (wave & 1) * 64;
    const int m0 = blockIdx.y * 128, n0 = blockIdx.x * 128;

    const short* Ab = (const short*)A + (size_t)blockIdx.z * 131072;
    const short* Bb = (const short*)B + (size_t)blockIdx.z * 131072;

    f4v acc[4][4];
#pragma unroll
    for (int i = 0; i < 4; ++i)
#pragma unroll
        for (int j = 0; j < 4; ++j) acc[i][j] = 0.f;

    const int r0 = tid >> 2,        s0 = (tid & 3) * 8;
    const int r1 = (tid + 256) >> 2, s1 = ((tid + 256) & 3) * 8;

    for (int k0 = 0; k0 < 256; k0 += 32) {
        *(s8v*)&As[r0][s0] = *(const s8v*)(Ab + (size_t)(m0 + r0) * 256 + k0 + s0);
        *(s8v*)&As[r1][s1] = *(const s8v*)(Ab + (size_t)(m0 + r1) * 256 + k0 + s1);
        *(s8v*)&Bs[r0][s0] = *(const s8v*)(Bb + (size_t)(n0 + r0) * 256 + k0 + s0);
        *(s8v*)&Bs[r1][s1] = *(const s8v*)(Bb + (size_t)(n0 + r1) * 256 + k0 + s1);
        __syncthreads();

        s8v af[4], bf[4];
#pragma unroll
        for (int i = 0; i < 4; ++i)
            af[i] = *(const s8v*)&As[wrow + i * 16 + l16][quad * 8];
#pragma unroll
        for (int j = 0; j < 4; ++j)
            bf[j] = *(const s8v*)&Bs[wcol + j * 16 + l16][quad * 8];
#pragma unroll
        for (int i = 0; i < 4; ++i)
#pragma unroll
            for (int j = 0; j < 4; ++j)
                acc[i][j] = __builtin_amdgcn_mfma_f32_16x16x32_bf16(
                    af[i], bf[j], acc[i][j], 0, 0, 0);
        __syncthreads();
    }

    __hip_bfloat16* Eb = E + (size_t)blockIdx.z * 262144;
    float* Sb = S + blockIdx.z * 512;
#pragma unroll
    for (int j = 0; j < 4; ++j) {
        const int n = n0 + wcol + j * 16 + l16;
        float colsum = 0.f;
#pragma unroll
        for (int i = 0; i < 4; ++i)
#pragma unroll
            for (int r = 0; r < 4; ++r) {
                const int m = m0 + wrow + i * 16 + quad * 4 + r;
                float v = acc[i][j][r] * Wm[(size_t)m * 512 + n];
                float e = __expf(v);
                colsum += e;
                Eb[(size_t)m * 512 + n] = __float2bfloat16(e);
            }
        atomicAdd(&Sb[n], colsum);
    }
}

// ---------------------------------------------------------------------------
// Fused xp GEMM (verified R10): C = A1@B[:, :256]^T + A2@B[:, 256:]^T + bias.
// ---------------------------------------------------------------------------
__global__ __launch_bounds__(256) void gemm_xp(
    const __hip_bfloat16* __restrict__ A1,   // x1b  [16384,256]
    const __hip_bfloat16* __restrict__ A2,   // ctxb [16384,256]
    const __hip_bfloat16* __restrict__ B,    // wihb [768,512]
    float* __restrict__ C,                   // xp   [16384,768]
    const float* __restrict__ bias)          // bih  [768]
{
    __shared__ short As[128][40];
    __shared__ short Bs[128][40];

    const int tid  = threadIdx.x;
    const int wave = tid >> 6, lane = tid & 63;
    const int quad = lane >> 4, l16 = lane & 15;
    const int wrow = (wave >> 1) * 64, wcol = (wave & 1) * 64;
    const int m0 = blockIdx.y * 128, n0 = blockIdx.x * 128;

    f4v acc[4][4];
#pragma unroll
    for (int i = 0; i < 4; ++i)
#pragma unroll
        for (int j = 0; j < 4; ++j) acc[i][j] = 0.f;

    const int r0 = tid >> 2,        s0 = (tid & 3) * 8;
    const int r1 = (tid + 256) >> 2, s1 = ((tid + 256) & 3) * 8;

    for (int k0 = 0; k0 < 512; k0 += 32) {
        const short* Ab = (const short*)(k0 < 256 ? A1 : A2);
        const int ka = k0 & 255;
        *(s8v*)&As[r0][s0] = *(const s8v*)(Ab + (size_t)(m0 + r0) * 256 + ka + s0);
        *(s8v*)&As[r1][s1] = *(const s8v*)(Ab + (size_t)(m0 + r1) * 256 + ka + s1);
        *(s8v*)&Bs[r0][s0] = *(const s8v*)((const short*)B + (size_t)(n0 + r0) * 512 + k0 + s0);
        *(s8v*)&Bs[r1][s1] = *(const s8v*)((const short*)B + (size_t)(n0 + r1) * 512 + k0 + s1);
        __syncthreads();

        s8v af[4], bf[4];
#pragma unroll
        for (int i = 0; i < 4; ++i)
            af[i] = *(const s8v*)&As[wrow + i * 16 + l16][quad * 8];
#pragma unroll
        for (int j = 0; j < 4; ++j)
            bf[j] = *(const s8v*)&Bs[wcol + j * 16 + l16][quad * 8];
#pragma unroll
        for (int i = 0; i < 4; ++i)
#pragma unroll
            for (int j = 0; j < 4; ++j)
                acc[i][j] = __builtin_amdgcn_mfma_f32_16x16x32_bf16(
                    af[i], bf[j], acc[i][j], 0, 0, 0);
        __syncthreads();
    }

#pragma unroll
    for (int i = 0; i < 4; ++i)
#pragma unroll
        for (int j = 0; j < 4; ++j)
#pragma unroll
            for (int r = 0; r < 4; ++r) {
                const int m = m0 + wrow + i * 16 + quad * 4 + r;
                const int n = n0 + wcol + j * 16 + l16;
                C[(size_t)m * 768 + n] = acc[i][j][r] + bias[n];
            }
}

// ---------------------------------------------------------------------------
// prolog: all input staging in ONE dispatch (verified R17).
// ---------------------------------------------------------------------------
__global__ __launch_bounds__(256) void prolog(
    const float* __restrict__ x1, const float* __restrict__ x2,
    const float* __restrict__ w1, const float* __restrict__ w2,
    const float* __restrict__ Dm,
    __hip_bfloat16* __restrict__ x1b, __hip_bfloat16* __restrict__ x2b,
    __hip_bfloat16* __restrict__ x2tb,
    __hip_bfloat16* __restrict__ w1b, __hip_bfloat16* __restrict__ w2b,
    __hip_bfloat16* __restrict__ Dtb,
    float* __restrict__ S)
{
    __shared__ float t[32][33];
    const int blk = blockIdx.x, tid = threadIdx.x;

    if (blk < 4096) {                       // ---- f2b(x1), n = 4194304
        const int i = (blk * 256 + tid) * 4;
        float4 v = *(const float4*)(x1 + i);
        x1b[i + 0] = __float2bfloat16(v.x);
        x1b[i + 1] = __float2bfloat16(v.y);
        x1b[i + 2] = __float2bfloat16(v.z);
        x1b[i + 3] = __float2bfloat16(v.w);
    } else if (blk < 8192) {                // ---- f2b_tr(x2): (8,16,32)
        const int idx = blk - 4096;
        const int bz = idx >> 7, by = (idx >> 3) & 15, bx = idx & 7;
        const int r0 = by * 32, c0 = bx * 32;
        const int tx = tid & 31, ty = tid >> 5;
        const float* Sx = x2 + (size_t)bz * 131072;
        __hip_bfloat16* Dc = x2b + (size_t)bz * 131072;
        __hip_bfloat16* Dd = x2tb + (size_t)bz * 131072;
#pragma unroll
        for (int i = 0; i < 32; i += 8) {
            const size_t idx2 = (size_t)(r0 + ty + i) * 256 + c0 + tx;
            float v = Sx[idx2];
            t[ty + i][tx] = v;
            Dc[idx2] = __float2bfloat16(v);
        }
        __syncthreads();
#pragma unroll
        for (int i = 0; i < 32; i += 8)
            Dd[(size_t)(c0 + ty + i) * 512 + r0 + tx] = __float2bfloat16(t[tx][ty + i]);
    } else if (blk < 8320) {                // ---- f2bw + zero S
        const int gid = (blk - 8192) * 256 + tid;
        if (gid < 4096)
            *(float4*)(S + gid * 4) = make_float4(0.f, 0.f, 0.f, 0.f);
        const int i = gid * 4;
        const float* s;
        __hip_bfloat16* d;
        if (i < 65536) { s = w1 + i;           d = w1b + i; }
        else           { s = w2 + (i - 65536); d = w2b + (i - 65536); }
        float4 v = *(const float4*)s;
        d[0] = __float2bfloat16(v.x);
        d[1] = __float2bfloat16(v.y);
        d[2] = __float2bfloat16(v.z);
        d[3] = __float2bfloat16(v.w);
    } else {                                // ---- tr_f2b(Dm): (8,8,1)
        const int idx = blk - 8320;
        const int by = idx >> 3, bx = idx & 7;
        const int r0 = by * 32, c0 = bx * 32;
        const int tx = tid & 31, ty = tid >> 5;
#pragma unroll
        for (int i = 0; i < 32; i += 8)
            t[ty + i][tx] = Dm[(size_t)(r0 + ty + i) * 256 + c0 + tx];
        __syncthreads();
#pragma unroll
        for (int i = 0; i < 32; i += 8)
            Dtb[(size_t)(c0 + ty + i) * 256 + r0 + tx] = __float2bfloat16(t[tx][ty + i]);
    }
}

// ---------------------------------------------------------------------------
// post_M: wih cast + softmax denominator into x2tb, one dispatch (R17).
// ---------------------------------------------------------------------------
__global__ __launch_bounds__(256) void post_M(
    const float* __restrict__ wih, __hip_bfloat16* __restrict__ wihb,
    __hip_bfloat16* __restrict__ X, const float* __restrict__ S)
{
    const int blk = blockIdx.x, tid = threadIdx.x;
    if (blk < 384) {                        // f2b(wih), n = 393216
        const int i = (blk * 256 + tid) * 4;
        float4 v = *(const float4*)(wih + i);
        wihb[i + 0] = __float2bfloat16(v.x);
        wihb[i + 1] = __float2bfloat16(v.y);
        wihb[i + 2] = __float2bfloat16(v.z);
        wihb[i + 3] = __float2bfloat16(v.w);
    } else {                                // sm_scale_x2
        const size_t tt = (size_t)(blk - 384) * 256 + tid;
        const size_t e0 = tt * 8;
        const int j0 = (int)(e0 & 511);
        const int b  = (int)(e0 >> 17);
        const float* Sb = S + b * 512 + j0;
        union { s8v v; __hip_bfloat16 h[8]; } u;
        u.v = *(const s8v*)(X + e0);
#pragma unroll
        for (int k = 0; k < 8; ++k)
            u.h[k] = __float2bfloat16(__bfloat162float(u.h[k]) / Sb[k]);
        *(s8v*)(X + e0) = u.v;
    }
}

// ---------------------------------------------------------------------------
// GRU, R19: R18's single-barrier in-wave-gate structure + gate-tail overlap.
//   8 waves; wave w owns elements [32w, 32w+32): acc[0+g]=r, acc[2+g]=z,
//   acc[4+g]=n rows (D row = 4*quad + rr, replicated across l16).
//   Gate lanes: l16<8; lane gates e = 32w + 16*(l16>>2) + 4*quad + (l16&3).
//   R19: all 8 bf fragments preloaded; MFMA burst split into tiles {0,2,4}
//   then {1,3,5}; the g==0 gate branch sits between the halves so its
//   ~150cyc trans chain overlaps the second 24-MFMA block. g==1 gates are
//   the only remaining serial tail. hhf double-buffered; ONE barrier/step.
// ---------------------------------------------------------------------------
__global__ __launch_bounds__(512, 2)
void gru_kernel(
    const float* __restrict__ xproj,   // [B, T, 768]
    const float* __restrict__ whh,     // [768, 256]
    const float* __restrict__ bhh,     // [768]
    float* __restrict__ out)           // [B, T, 256]
{
    const int b    = blockIdx.x;
    const int tid  = threadIdx.x;
    const int wave = tid >> 6, lane = tid & 63;
    const int quad = lane >> 4, l16 = lane & 15;

    __shared__ __align__(16) _Float16 hhf[2][256];   // h (f16), double-buffered

    const int w32 = 32 * wave;
    const int rowb[6] = { w32, w32 + 16,
                          256 + w32, 256 + w32 + 16,
                          512 + w32, 512 + w32 + 16 };

    // Weight A-fragments: wreg[i][kk] = whh[rowb[i]+l16][kk*32+quad*8 .. +7]
    h8v wreg[6][8];
#pragma unroll
    for (int i = 0; i < 6; ++i) {
        const float* rp = whh + (size_t)(rowb[i] + l16) * 256 + quad * 8;
#pragma unroll
        for (int kk = 0; kk < 8; ++kk) {
            float4 t0 = *(const float4*)(rp + kk * 32);
            float4 t1 = *(const float4*)(rp + kk * 32 + 4);
            h8v f;
            f[0] = (_Float16)t0.x; f[1] = (_Float16)t0.y;
            f[2] = (_Float16)t0.z; f[3] = (_Float16)t0.w;
            f[4] = (_Float16)t1.x; f[5] = (_Float16)t1.y;
            f[6] = (_Float16)t1.z; f[7] = (_Float16)t1.w;
            wreg[i][kk] = f;
        }
    }

    const float* xb = xproj + (size_t)b * 512 * 768;
    float*       ob = out   + (size_t)b * 512 * 256;

    // Gate-lane assignment: one lane per element, registers hold its r/z/n.
    const bool act = (l16 < 8);
    const int g  = (l16 >> 2) & 1;
    const int rr = l16 & 3;
    const int e  = w32 + 16 * g + 4 * quad + rr;

    float hA = 0.f, xr = 0.f, xz = 0.f, xn = 0.f;
    float br = 0.f, bz = 0.f, bn = 0.f;
    if (act) {
        br = bhh[e]; bz = bhh[256 + e]; bn = bhh[512 + e];
        xr = xb[e];  xz = xb[256 + e];  xn = xb[512 + e];
    }
    if (tid < 256) hhf[0][tid] = (_Float16)0.f;
    bar_lds();

    for (int t = 0; t < 512; ++t) {
        // ---- x(t+1) prefetch (gate lanes only): in flight across the burst
        float nxr = 0.f, nxz = 0.f, nxn = 0.f;
        if (act) {
            const float* xpn = xb + (size_t)((t + 1) & 511) * 768;
            nxr = xpn[e]; nxz = xpn[256 + e]; nxn = xpn[512 + e];
        }

        // ---- preload ALL 8 B-fragments of h (lgkm drain front-loaded) ------
        const _Float16* hc = hhf[t & 1];
        h8v bf[8];
#pragma unroll
        for (int kk = 0; kk < 8; ++kk)
            bf[kk] = *(const h8v*)&hc[kk * 32 + quad * 8];

        f4v acc[6];
#pragma unroll
        for (int i = 0; i < 6; ++i) acc[i] = 0.f;

        // ---- MFMA half 1: tiles {0,2,4} (r/z/n rows for g==0 elements) -----
#pragma unroll
        for (int kk = 0; kk < 8; ++kk) {
            acc[0] = __builtin_amdgcn_mfma_f32_16x16x32_f16(
                wreg[0][kk], bf[kk], acc[0], 0, 0, 0);
            acc[2] = __builtin_amdgcn_mfma_f32_16x16x32_f16(
                wreg[2][kk], bf[kk], acc[2], 0, 0, 0);
            acc[4] = __builtin_amdgcn_mfma_f32_16x16x32_f16(
                wreg[4][kk], bf[kk], acc[4], 0, 0, 0);
        }

        // ---- g==0 gates: trans chain overlaps MFMA half 2 ------------------
        if (act && g == 0) {
            float hpr = sel4(acc[0], rr);
            float hpz = sel4(acc[2], rr);
            float hpn = sel4(acc[4], rr);
            float r = fast_sig(xr + br + hpr);
            float z = fast_sig(xz + bz + hpz);
            float n = fast_tanh(xn + r * (hpn + bn));
            float h = (1.f - z) * n + z * hA;
            hA = h;
            hhf[(t + 1) & 1][e] = (_Float16)h;     // other buffer: no race
            ob[(size_t)t * 256 + e] = h;
            xr = nxr; xz = nxz; xn = nxn;
        }

        // ---- MFMA half 2: tiles {1,3,5} (rows for g==1 elements) -----------
#pragma unroll
        for (int kk = 0; kk < 8; ++kk) {
            acc[1] = __builtin_amdgcn_mfma_f32_16x16x32_f16(
                wreg[1][kk], bf[kk], acc[1], 0, 0, 0);
            acc[3] = __builtin_amdgcn_mfma_f32_16x16x32_f16(
                wreg[3][kk], bf[kk], acc[3], 0, 0, 0);
            acc[5] = __builtin_amdgcn_mfma_f32_16x16x32_f16(
                wreg[5][kk], bf[kk], acc[5], 0, 0, 0);
        }

        // ---- g==1 gates: the only serial tail ------------------------------
        if (act && g == 1) {
            float hpr = sel4(acc[1], rr);
            float hpz = sel4(acc[3], rr);
            float hpn = sel4(acc[5], rr);
            float r = fast_sig(xr + br + hpr);
            float z = fast_sig(xz + bz + hpz);
            float n = fast_tanh(xn + r * (hpn + bn));
            float h = (1.f - z) * n + z * hA;
            hA = h;
            hhf[(t + 1) & 1][e] = (_Float16)h;
            ob[(size_t)t * 256 + e] = h;
            xr = nxr; xz = nxz; xn = nxn;
        }

        bar_lds();   // single barrier: hhf[nxt] visible to all waves
    }
}

extern "C" void kernel_launch(void* const* d_in, const int* in_sizes, int n_in,
                              void* d_out, int out_size, void* d_ws, size_t ws_size,
                              hipStream_t stream)
{
    (void)in_sizes; (void)n_in; (void)out_size; (void)ws_size;

    const float* x1  = (const float*)d_in[0];   // [32,512,256]
    const float* x2  = (const float*)d_in[1];   // [32,512,256]
    const float* w1  = (const float*)d_in[2];   // [256,256]
    const float* w2  = (const float*)d_in[3];   // [256,256]
    const float* Dm  = (const float*)d_in[4];   // [256,256]
    const float* Wm  = (const float*)d_in[5];   // [512,512]
    const float* wih = (const float*)d_in[6];   // [768,512]
    const float* whh = (const float*)d_in[7];   // [768,256]
    const float* bih = (const float*)d_in[8];   // [768]
    const float* bhh = (const float*)d_in[9];   // [768]
    float* out = (float*)d_out;

    // Workspace aliasing (R15/R17: R13 base + a1db at +8MB).
    char* base = (char*)d_ws;
    __hip_bfloat16* w1b  = (__hip_bfloat16*)(base + 0);
    __hip_bfloat16* w2b  = (__hip_bfloat16*)(base + 131072);
    __hip_bfloat16* Dtb  = (__hip_bfloat16*)(base + 262144);
    float*          Ssum = (float*)(base + 1048576);        // [32*512] fp32
    float*          xp   = (float*)(base + 0);
    __hip_bfloat16* a1db = (__hip_bfloat16*)(base + 8388608);
    __hip_bfloat16* a1b  = (__hip_bfloat16*)(base + 33554432);
    __hip_bfloat16* Msb  = (__hip_bfloat16*)(base + 33554432);
    __hip_bfloat16* x1b  = (__hip_bfloat16*)(base + 50331648);
    __hip_bfloat16* x2b  = (__hip_bfloat16*)(base + 58720256);
    __hip_bfloat16* ctxb = (__hip_bfloat16*)(base + 58720256);
    __hip_bfloat16* x2tb = (__hip_bfloat16*)(base + 67108864);
    __hip_bfloat16* a2b  = (__hip_bfloat16*)(base + 75497472);
    __hip_bfloat16* wihb = (__hip_bfloat16*)(base + 75497472);

    dim3 blk(256);

    // All input staging in one dispatch
    prolog<<<dim3(8384), blk, 0, stream>>>(
        x1, x2, w1, w2, Dm, x1b, x2b, x2tb, w1b, w2b, Dtb, Ssum);

    // a1 = relu(x1b@w1^T), a2 = relu(x2b@w2^T) in ONE launch via z-strides.
    gemm_bf16<<<dim3(2, 128, 2), blk, 0, stream>>>(
        x1b, 256, 4194304, w1b, 256, 65536, a1b, 256, 20971520, 256,
        nullptr, nullptr, 0, 1, 0, 1);
    gemm_bf16<<<dim3(2, 128, 1), blk, 0, stream>>>(
        a1b, 256, 0, Dtb, 256, 0, a1db, 256, 0, 256,
        nullptr, nullptr, 0, 0, 0, 1);
    // M GEMM with fused exp + column-sum atomics: Msb = exp((a1d@a2^T)*W)
    gemm_M<<<dim3(4, 4, 32), blk, 0, stream>>>(a1db, a2b, Msb, Wm, Ssum);
    // wih cast (a2b dead) + softmax denominator into x2tb, one dispatch
    post_M<<<dim3(2432), blk, 0, stream>>>(wih, wihb, x2tb, Ssum);
    gemm_bf16<<<dim3(2, 4, 32), blk, 0, stream>>>(
        Msb, 512, 262144, x2tb, 512, 131072, ctxb, 256, 131072, 512,
        nullptr, nullptr, 0, 0, 0, 1);
    // Fused xp = x1b @ wih[:, :256]^T + ctxb @ wih[:, 256:]^T + bih
    gemm_xp<<<dim3(6, 128, 1), blk, 0, stream>>>(x1b, ctxb, wihb, xp, bih);
    gru_kernel<<<dim3(32), dim3(512), 0, stream>>>(xp, whh, bhh, out);
}

// Round 14
// 711.733 us; speedup vs baseline: 1.2091x; 1.2091x over previous
//
#include <hip/hip_runtime.h>
#include <hip/hip_bf16.h>
#include <cstdint>
#include <cstddef>

// ---------------------------------------------------------------------------
// EnrichAttention: B=32, L1=L2=512, H=A=256, 3H=768, 2H=512
// R20: REVERT of R19's split-burst GRU (666us; in-order issue within a wave
//      means a wave's gate chain cannot overlap its own later MFMAs — the
//      split only added dependency stalls). GRU restored byte-for-byte to
//      the verified R18 kernel (522us GRU, 714.0us total = session best):
//      single barrier, in-wave gates after the full 6-chain MFMA burst.
//      All non-GRU kernels byte-identical to R17/R18.
// ---------------------------------------------------------------------------

typedef short s8v __attribute__((ext_vector_type(8)));      // 8 bf16 (4 VGPRs)
typedef float f4v __attribute__((ext_vector_type(4)));      // MFMA accumulator
typedef _Float16 h8v __attribute__((ext_vector_type(8)));   // 8 f16 (4 VGPRs)

#if __has_builtin(__builtin_amdgcn_sched_barrier)
#define SCHED_FENCE() __builtin_amdgcn_sched_barrier(0)
#else
#define SCHED_FENCE() asm volatile("" ::: "memory")
#endif

// Workgroup barrier waiting only on LDS (lgkmcnt). Only hhf (LDS) carries
// cross-thread deps in the GRU loop; global loads stay in flight across it.
__device__ __forceinline__ void bar_lds() {
    asm volatile("s_waitcnt lgkmcnt(0)\n\ts_barrier" ::: "memory");
}

__device__ __forceinline__ float fast_exp(float x) {
#if __has_builtin(__builtin_amdgcn_exp2f)
    return __builtin_amdgcn_exp2f(x * 1.44269504f);
#else
    return __expf(x);
#endif
}
__device__ __forceinline__ float fast_rcp(float x) {
#if __has_builtin(__builtin_amdgcn_rcpf)
    return __builtin_amdgcn_rcpf(x);
#else
    return 1.f / x;
#endif
}
__device__ __forceinline__ float fast_sig(float x) { return fast_rcp(1.f + fast_exp(-x)); }
__device__ __forceinline__ float fast_tanh(float x) {
    return 1.f - 2.f * fast_rcp(1.f + fast_exp(2.f * x));
}

// Dynamic extract from f4v with compile-time vector indices only (rule #20:
// no runtime-indexed array -> no scratch; lowers to 3 v_cndmask).
__device__ __forceinline__ float sel4(f4v v, int rr) {
    float a = (rr & 1) ? v[1] : v[0];
    float b = (rr & 1) ? v[3] : v[2];
    return (rr & 2) ? b : a;
}

// ---------------------------------------------------------------------------
// MFMA bf16 NT GEMM: C[M,N] = A[M,K] * B[N,K]^T. (Verified in R5.)
// ---------------------------------------------------------------------------
__global__ __launch_bounds__(256) void gemm_bf16(
    const __hip_bfloat16* __restrict__ A, int lda, long long sA,
    const __hip_bfloat16* __restrict__ B, int ldb, long long sB,
    void* __restrict__ C, int ldc, long long sC,
    int K,
    const float* __restrict__ bias,
    const float* __restrict__ emul, int ldmul,
    int relu, int accum, int out_bf16)
{
    __shared__ short As[128][40];
    __shared__ short Bs[128][40];

    const int tid  = threadIdx.x;
    const int wave = tid >> 6, lane = tid & 63;
    const int quad = lane >> 4, l16 = lane & 15;
    const int wrow = (wave >> 1) * 64, wcol = (wave & 1) * 64;
    const int m0 = blockIdx.y * 128, n0 = blockIdx.x * 128;

    const short* Ab = (const short*)A + (size_t)blockIdx.z * sA;
    const short* Bb = (const short*)B + (size_t)blockIdx.z * sB;

    f4v acc[4][4];
#pragma unroll
    for (int i = 0; i < 4; ++i)
#pragma unroll
        for (int j = 0; j < 4; ++j) acc[i][j] = 0.f;

    const int r0 = tid >> 2,        s0 = (tid & 3) * 8;
    const int r1 = (tid + 256) >> 2, s1 = ((tid + 256) & 3) * 8;

    for (int k0 = 0; k0 < K; k0 += 32) {
        *(s8v*)&As[r0][s0] = *(const s8v*)(Ab + (size_t)(m0 + r0) * lda + k0 + s0);
        *(s8v*)&As[r1][s1] = *(const s8v*)(Ab + (size_t)(m0 + r1) * lda + k0 + s1);
        *(s8v*)&Bs[r0][s0] = *(const s8v*)(Bb + (size_t)(n0 + r0) * ldb + k0 + s0);
        *(s8v*)&Bs[r1][s1] = *(const s8v*)(Bb + (size_t)(n0 + r1) * ldb + k0 + s1);
        __syncthreads();

        s8v af[4], bf[4];
#pragma unroll
        for (int i = 0; i < 4; ++i)
            af[i] = *(const s8v*)&As[wrow + i * 16 + l16][quad * 8];
#pragma unroll
        for (int j = 0; j < 4; ++j)
            bf[j] = *(const s8v*)&Bs[wcol + j * 16 + l16][quad * 8];
#pragma unroll
        for (int i = 0; i < 4; ++i)
#pragma unroll
            for (int j = 0; j < 4; ++j)
                acc[i][j] = __builtin_amdgcn_mfma_f32_16x16x32_bf16(
                    af[i], bf[j], acc[i][j], 0, 0, 0);
        __syncthreads();
    }

    float* Cf = (float*)C + (size_t)blockIdx.z * sC;
    __hip_bfloat16* Cb = (__hip_bfloat16*)C + (size_t)blockIdx.z * sC;
#pragma unroll
    for (int i = 0; i < 4; ++i)
#pragma unroll
        for (int j = 0; j < 4; ++j)
#pragma unroll
            for (int r = 0; r < 4; ++r) {
                const int m = m0 + wrow + i * 16 + quad * 4 + r;
                const int n = n0 + wcol + j * 16 + l16;
                float v = acc[i][j][r];
                if (bias)  v += bias[n];
                if (accum) v += Cf[(size_t)m * ldc + n];
                if (emul)  v *= emul[(size_t)m * ldmul + n];
                if (relu)  v = fmaxf(v, 0.f);
                if (out_bf16) Cb[(size_t)m * ldc + n] = __float2bfloat16(v);
                else          Cf[(size_t)m * ldc + n] = v;
            }
}

// ---------------------------------------------------------------------------
// M GEMM + fused softmax numerator (verified R13):
//   E = bf16(exp((a1d@a2^T)*W)); S[b][n] += column sums (fp32 atomics).
// ---------------------------------------------------------------------------
__global__ __launch_bounds__(256) void gemm_M(
    const __hip_bfloat16* __restrict__ A,   // a1db [32][512][256]
    const __hip_bfloat16* __restrict__ B,   // a2b  [32][512][256]
    __hip_bfloat16* __restrict__ E,         // Msb  [32][512][512]
    const float* __restrict__ Wm,           // [512,512]
    float* __restrict__ S)                  // [32][512] (pre-zeroed)
{
    __shared__ short As[128][40];
    __shared__ short Bs[128][40];

    const int tid  = threadIdx.x;
    const int wave = tid >> 6, lane = tid & 63;
    const int quad = lane >> 4, l16 = lane & 15;
    const int wrow = (wave >> 1) * 64, wcol = (wave & 1) * 64;
    const int m0 = blockIdx.y * 128, n0 = blockIdx.x * 128;

    const short* Ab = (const short*)A + (size_t)blockIdx.z * 131072;
    const short* Bb = (const short*)B + (size_t)blockIdx.z * 131072;

    f4v acc[4][4];
#pragma unroll
    for (int i = 0; i < 4; ++i)
#pragma unroll
        for (int j = 0; j < 4; ++j) acc[i][j] = 0.f;

    const int r0 = tid >> 2,        s0 = (tid & 3) * 8;
    const int r1 = (tid + 256) >> 2, s1 = ((tid + 256) & 3) * 8;

    for (int k0 = 0; k0 < 256; k0 += 32) {
        *(s8v*)&As[r0][s0] = *(const s8v*)(Ab + (size_t)(m0 + r0) * 256 + k0 + s0);
        *(s8v*)&As[r1][s1] = *(const s8v*)(Ab + (size_t)(m0 + r1) * 256 + k0 + s1);
        *(s8v*)&Bs[r0][s0] = *(const s8v*)(Bb + (size_t)(n0 + r0) * 256 + k0 + s0);
        *(s8v*)&Bs[r1][s1] = *(const s8v*)(Bb + (size_t)(n0 + r1) * 256 + k0 + s1);
        __syncthreads();

        s8v af[4], bf[4];
#pragma unroll
        for (int i = 0; i < 4; ++i)
            af[i] = *(const s8v*)&As[wrow + i * 16 + l16][quad * 8];
#pragma unroll
        for (int j = 0; j < 4; ++j)
            bf[j] = *(const s8v*)&Bs[wcol + j * 16 + l16][quad * 8];
#pragma unroll
        for (int i = 0; i < 4; ++i)
#pragma unroll
            for (int j = 0; j < 4; ++j)
                acc[i][j] = __builtin_amdgcn_mfma_f32_16x16x32_bf16(
                    af[i], bf[j], acc[i][j], 0, 0, 0);
        __syncthreads();
    }

    __hip_bfloat16* Eb = E + (size_t)blockIdx.z * 262144;
    float* Sb = S + blockIdx.z * 512;
#pragma unroll
    for (int j = 0; j < 4; ++j) {
        const int n = n0 + wcol + j * 16 + l16;
        float colsum = 0.f;
#pragma unroll
        for (int i = 0; i < 4; ++i)
#pragma unroll
            for (int r = 0; r < 4; ++r) {
                const int m = m0 + wrow + i * 16 + quad * 4 + r;
                float v = acc[i][j][r] * Wm[(size_t)m * 512 + n];
                float e = __expf(v);
                colsum += e;
                Eb[(size_t)m * 512 + n] = __float2bfloat16(e);
            }
        atomicAdd(&Sb[n], colsum);
    }
}

// ---------------------------------------------------------------------------
// Fused xp GEMM (verified R10): C = A1@B[:, :256]^T + A2@B[:, 256:]^T + bias.
// ---------------------------------------------------------------------------
__global__ __launch_bounds__(256) void gemm_xp(
    const __hip_bfloat16* __restrict__ A1,   // x1b  [16384,256]
    const __hip_bfloat16* __restrict__ A2,   // ctxb [16384,256]
    const __hip_bfloat16* __restrict__ B,    // wihb [768,512]
    float* __restrict__ C,                   // xp   [16384,768]
    const float* __restrict__ bias)          // bih  [768]
{
    __shared__ short As[128][40];
    __shared__ short Bs[128][40];

    const int tid  = threadIdx.x;
    const int wave = tid >> 6, lane = tid & 63;
    const int quad = lane >> 4, l16 = lane & 15;
    const int wrow = (wave >> 1) * 64, wcol = (wave & 1) * 64;
    const int m0 = blockIdx.y * 128, n0 = blockIdx.x * 128;

    f4v acc[4][4];
#pragma unroll
    for (int i = 0; i < 4; ++i)
#pragma unroll
        for (int j = 0; j < 4; ++j) acc[i][j] = 0.f;

    const int r0 = tid >> 2,        s0 = (tid & 3) * 8;
    const int r1 = (tid + 256) >> 2, s1 = ((tid + 256) & 3) * 8;

    for (int k0 = 0; k0 < 512; k0 += 32) {
        const short* Ab = (const short*)(k0 < 256 ? A1 : A2);
        const int ka = k0 & 255;
        *(s8v*)&As[r0][s0] = *(const s8v*)(Ab + (size_t)(m0 + r0) * 256 + ka + s0);
        *(s8v*)&As[r1][s1] = *(const s8v*)(Ab + (size_t)(m0 + r1) * 256 + ka + s1);
        *(s8v*)&Bs[r0][s0] = *(const s8v*)((const short*)B + (size_t)(n0 + r0) * 512 + k0 + s0);
        *(s8v*)&Bs[r1][s1] = *(const s8v*)((const short*)B + (size_t)(n0 + r1) * 512 + k0 + s1);
        __syncthreads();

        s8v af[4], bf[4];
#pragma unroll
        for (int i = 0; i < 4; ++i)
            af[i] = *(const s8v*)&As[wrow + i * 16 + l16][quad * 8];
#pragma unroll
        for (int j = 0; j < 4; ++j)
            bf[j] = *(const s8v*)&Bs[wcol + j * 16 + l16][quad * 8];
#pragma unroll
        for (int i = 0; i < 4; ++i)
#pragma unroll
            for (int j = 0; j < 4; ++j)
                acc[i][j] = __builtin_amdgcn_mfma_f32_16x16x32_bf16(
                    af[i], bf[j], acc[i][j], 0, 0, 0);
        __syncthreads();
    }

#pragma unroll
    for (int i = 0; i < 4; ++i)
#pragma unroll
        for (int j = 0; j < 4; ++j)
#pragma unroll
            for (int r = 0; r < 4; ++r) {
                const int m = m0 + wrow + i * 16 + quad * 4 + r;
                const int n = n0 + wcol + j * 16 + l16;
                C[(size_t)m * 768 + n] = acc[i][j][r] + bias[n];
            }
}

// ---------------------------------------------------------------------------
// prolog: all input staging in ONE dispatch (verified R17).
// ---------------------------------------------------------------------------
__global__ __launch_bounds__(256) void prolog(
    const float* __restrict__ x1, const float* __restrict__ x2,
    const float* __restrict__ w1, const float* __restrict__ w2,
    const float* __restrict__ Dm,
    __hip_bfloat16* __restrict__ x1b, __hip_bfloat16* __restrict__ x2b,
    __hip_bfloat16* __restrict__ x2tb,
    __hip_bfloat16* __restrict__ w1b, __hip_bfloat16* __restrict__ w2b,
    __hip_bfloat16* __restrict__ Dtb,
    float* __restrict__ S)
{
    __shared__ float t[32][33];
    const int blk = blockIdx.x, tid = threadIdx.x;

    if (blk < 4096) {                       // ---- f2b(x1), n = 4194304
        const int i = (blk * 256 + tid) * 4;
        float4 v = *(const float4*)(x1 + i);
        x1b[i + 0] = __float2bfloat16(v.x);
        x1b[i + 1] = __float2bfloat16(v.y);
        x1b[i + 2] = __float2bfloat16(v.z);
        x1b[i + 3] = __float2bfloat16(v.w);
    } else if (blk < 8192) {                // ---- f2b_tr(x2): (8,16,32)
        const int idx = blk - 4096;
        const int bz = idx >> 7, by = (idx >> 3) & 15, bx = idx & 7;
        const int r0 = by * 32, c0 = bx * 32;
        const int tx = tid & 31, ty = tid >> 5;
        const float* Sx = x2 + (size_t)bz * 131072;
        __hip_bfloat16* Dc = x2b + (size_t)bz * 131072;
        __hip_bfloat16* Dd = x2tb + (size_t)bz * 131072;
#pragma unroll
        for (int i = 0; i < 32; i += 8) {
            const size_t idx2 = (size_t)(r0 + ty + i) * 256 + c0 + tx;
            float v = Sx[idx2];
            t[ty + i][tx] = v;
            Dc[idx2] = __float2bfloat16(v);
        }
        __syncthreads();
#pragma unroll
        for (int i = 0; i < 32; i += 8)
            Dd[(size_t)(c0 + ty + i) * 512 + r0 + tx] = __float2bfloat16(t[tx][ty + i]);
    } else if (blk < 8320) {                // ---- f2bw + zero S
        const int gid = (blk - 8192) * 256 + tid;
        if (gid < 4096)
            *(float4*)(S + gid * 4) = make_float4(0.f, 0.f, 0.f, 0.f);
        const int i = gid * 4;
        const float* s;
        __hip_bfloat16* d;
        if (i < 65536) { s = w1 + i;           d = w1b + i; }
        else           { s = w2 + (i - 65536); d = w2b + (i - 65536); }
        float4 v = *(const float4*)s;
        d[0] = __float2bfloat16(v.x);
        d[1] = __float2bfloat16(v.y);
        d[2] = __float2bfloat16(v.z);
        d[3] = __float2bfloat16(v.w);
    } else {                                // ---- tr_f2b(Dm): (8,8,1)
        const int idx = blk - 8320;
        const int by = idx >> 3, bx = idx & 7;
        const int r0 = by * 32, c0 = bx * 32;
        const int tx = tid & 31, ty = tid >> 5;
#pragma unroll
        for (int i = 0; i < 32; i += 8)
            t[ty + i][tx] = Dm[(size_t)(r0 + ty + i) * 256 + c0 + tx];
        __syncthreads();
#pragma unroll
        for (int i = 0; i < 32; i += 8)
            Dtb[(size_t)(c0 + ty + i) * 256 + r0 + tx] = __float2bfloat16(t[tx][ty + i]);
    }
}

// ---------------------------------------------------------------------------
// post_M: wih cast + softmax denominator into x2tb, one dispatch (R17).
// ---------------------------------------------------------------------------
__global__ __launch_bounds__(256) void post_M(
    const float* __restrict__ wih, __hip_bfloat16* __restrict__ wihb,
    __hip_bfloat16* __restrict__ X, const float* __restrict__ S)
{
    const int blk = blockIdx.x, tid = threadIdx.x;
    if (blk < 384) {                        // f2b(wih), n = 393216
        const int i = (blk * 256 + tid) * 4;
        float4 v = *(const float4*)(wih + i);
        wihb[i + 0] = __float2bfloat16(v.x);
        wihb[i + 1] = __float2bfloat16(v.y);
        wihb[i + 2] = __float2bfloat16(v.z);
        wihb[i + 3] = __float2bfloat16(v.w);
    } else {                                // sm_scale_x2
        const size_t tt = (size_t)(blk - 384) * 256 + tid;
        const size_t e0 = tt * 8;
        const int j0 = (int)(e0 & 511);
        const int b  = (int)(e0 >> 17);
        const float* Sb = S + b * 512 + j0;
        union { s8v v; __hip_bfloat16 h[8]; } u;
        u.v = *(const s8v*)(X + e0);
#pragma unroll
        for (int k = 0; k < 8; ++k)
            u.h[k] = __float2bfloat16(__bfloat162float(u.h[k]) / Sb[k]);
        *(s8v*)(X + e0) = u.v;
    }
}

// ---------------------------------------------------------------------------
// GRU (verified R18, 522us GRU / 714.0us total): single-barrier in-wave-gate.
//   8 waves; wave w owns elements [32w, 32w+32): 6 acc tiles:
//   acc[0+g]=r rows {32w+16g..}, acc[2+g]=z, acc[4+g]=n; D-fragment row =
//   4*quad + rr, replicated across l16.
//   Gate lanes: l16<8; lane gates e = 32w + 16*(l16>>2) + 4*quad + (l16&3)
//   from its OWN registers (sel4 = cndmask trees; no LDS round-trip).
//   h double-buffered in LDS f16 (hhf[2][256]): step t reads [t&1], gate
//   lanes write [(t+1)&1] -> ONE lgkm barrier per step.
//   x(t+1) (12B per element, gate lanes only) prefetched before the burst.
//   DO NOT: split the MFMA burst around the gates (R19, 666us — in-order
//   issue within a wave), widen to 16 waves (R16, 847us), or gate on a
//   separate wave via hp LDS round-trip (R15, 663us).
// ---------------------------------------------------------------------------
__global__ __launch_bounds__(512, 2)
void gru_kernel(
    const float* __restrict__ xproj,   // [B, T, 768]
    const float* __restrict__ whh,     // [768, 256]
    const float* __restrict__ bhh,     // [768]
    float* __restrict__ out)           // [B, T, 256]
{
    const int b    = blockIdx.x;
    const int tid  = threadIdx.x;
    const int wave = tid >> 6, lane = tid & 63;
    const int quad = lane >> 4, l16 = lane & 15;

    __shared__ __align__(16) _Float16 hhf[2][256];   // h (f16), double-buffered

    const int w32 = 32 * wave;
    const int rowb[6] = { w32, w32 + 16,
                          256 + w32, 256 + w32 + 16,
                          512 + w32, 512 + w32 + 16 };

    // Weight A-fragments: wreg[i][kk] = whh[rowb[i]+l16][kk*32+quad*8 .. +7]
    h8v wreg[6][8];
#pragma unroll
    for (int i = 0; i < 6; ++i) {
        const float* rp = whh + (size_t)(rowb[i] + l16) * 256 + quad * 8;
#pragma unroll
        for (int kk = 0; kk < 8; ++kk) {
            float4 t0 = *(const float4*)(rp + kk * 32);
            float4 t1 = *(const float4*)(rp + kk * 32 + 4);
            h8v f;
            f[0] = (_Float16)t0.x; f[1] = (_Float16)t0.y;
            f[2] = (_Float16)t0.z; f[3] = (_Float16)t0.w;
            f[4] = (_Float16)t1.x; f[5] = (_Float16)t1.y;
            f[6] = (_Float16)t1.z; f[7] = (_Float16)t1.w;
            wreg[i][kk] = f;
        }
    }

    const float* xb = xproj + (size_t)b * 512 * 768;
    float*       ob = out   + (size_t)b * 512 * 256;

    // Gate-lane assignment: one lane per element, registers hold its r/z/n.
    const bool act = (l16 < 8);
    const int g  = (l16 >> 2) & 1;
    const int rr = l16 & 3;
    const int e  = w32 + 16 * g + 4 * quad + rr;

    float hA = 0.f, xr = 0.f, xz = 0.f, xn = 0.f;
    float br = 0.f, bz = 0.f, bn = 0.f;
    if (act) {
        br = bhh[e]; bz = bhh[256 + e]; bn = bhh[512 + e];
        xr = xb[e];  xz = xb[256 + e];  xn = xb[512 + e];
    }
    if (tid < 256) hhf[0][tid] = (_Float16)0.f;
    bar_lds();

    for (int t = 0; t < 512; ++t) {
        // ---- x(t+1) prefetch (gate lanes only): in flight across the burst
        float nxr = 0.f, nxz = 0.f, nxn = 0.f;
        if (act) {
            const float* xpn = xb + (size_t)((t + 1) & 511) * 768;
            nxr = xpn[e]; nxz = xpn[256 + e]; nxn = xpn[512 + e];
        }

        // ---- MFMA burst: hp(rows of wave w) = whh_rows @ h ------------------
        f4v acc[6];
#pragma unroll
        for (int i = 0; i < 6; ++i) acc[i] = 0.f;

        const _Float16* hc = hhf[t & 1];
        h8v bf_cur = *(const h8v*)&hc[quad * 8];
#pragma unroll
        for (int kk = 0; kk < 8; ++kk) {
            h8v bf_nxt = bf_cur;
            if (kk < 7) bf_nxt = *(const h8v*)&hc[(kk + 1) * 32 + quad * 8];
#pragma unroll
            for (int i = 0; i < 6; ++i)
                acc[i] = __builtin_amdgcn_mfma_f32_16x16x32_f16(
                    wreg[i][kk], bf_cur, acc[i], 0, 0, 0);
            SCHED_FENCE();   // bound bf live range, keep pipeline 1-deep
            bf_cur = bf_nxt;
        }

        // ---- in-register gates (compile-time vector indices via sel4) ------
        {
            f4v vr = g ? acc[1] : acc[0];
            f4v vz = g ? acc[3] : acc[2];
            f4v vn = g ? acc[5] : acc[4];
            float hpr = sel4(vr, rr);
            float hpz = sel4(vz, rr);
            float hpn = sel4(vn, rr);
            if (act) {
                float r = fast_sig(xr + br + hpr);
                float z = fast_sig(xz + bz + hpz);
                float n = fast_tanh(xn + r * (hpn + bn));
                float h = (1.f - z) * n + z * hA;
                hA = h;
                hhf[(t + 1) & 1][e] = (_Float16)h;
                ob[(size_t)t * 256 + e] = h;
                xr = nxr; xz = nxz; xn = nxn;   // vmcnt wait lands here
            }
        }
        bar_lds();   // single barrier: hhf[nxt] visible to all waves
    }
}

extern "C" void kernel_launch(void* const* d_in, const int* in_sizes, int n_in,
                              void* d_out, int out_size, void* d_ws, size_t ws_size,
                              hipStream_t stream)
{
    (void)in_sizes; (void)n_in; (void)out_size; (void)ws_size;

    const float* x1  = (const float*)d_in[0];   // [32,512,256]
    const float* x2  = (const float*)d_in[1];   // [32,512,256]
    const float* w1  = (const float*)d_in[2];   // [256,256]
    const float* w2  = (const float*)d_in[3];   // [256,256]
    const float* Dm  = (const float*)d_in[4];   // [256,256]
    const float* Wm  = (const float*)d_in[5];   // [512,512]
    const float* wih = (const float*)d_in[6];   // [768,512]
    const float* whh = (const float*)d_in[7];   // [768,256]
    const float* bih = (const float*)d_in[8];   // [768]
    const float* bhh = (const float*)d_in[9];   // [768]
    float* out = (float*)d_out;

    // Workspace aliasing (R15/R17: R13 base + a1db at +8MB).
    char* base = (char*)d_ws;
    __hip_bfloat16* w1b  = (__hip_bfloat16*)(base + 0);
    __hip_bfloat16* w2b  = (__hip_bfloat16*)(base + 131072);
    __hip_bfloat16* Dtb  = (__hip_bfloat16*)(base + 262144);
    float*          Ssum = (float*)(base + 1048576);        // [32*512] fp32
    float*          xp   = (float*)(base + 0);
    __hip_bfloat16* a1db = (__hip_bfloat16*)(base + 8388608);
    __hip_bfloat16* a1b  = (__hip_bfloat16*)(base + 33554432);
    __hip_bfloat16* Msb  = (__hip_bfloat16*)(base + 33554432);
    __hip_bfloat16* x1b  = (__hip_bfloat16*)(base + 50331648);
    __hip_bfloat16* x2b  = (__hip_bfloat16*)(base + 58720256);
    __hip_bfloat16* ctxb = (__hip_bfloat16*)(base + 58720256);
    __hip_bfloat16* x2tb = (__hip_bfloat16*)(base + 67108864);
    __hip_bfloat16* a2b  = (__hip_bfloat16*)(base + 75497472);
    __hip_bfloat16* wihb = (__hip_bfloat16*)(base + 75497472);

    dim3 blk(256);

    // All input staging in one dispatch
    prolog<<<dim3(8384), blk, 0, stream>>>(
        x1, x2, w1, w2, Dm, x1b, x2b, x2tb, w1b, w2b, Dtb, Ssum);

    // a1 = relu(x1b@w1^T), a2 = relu(x2b@w2^T) in ONE launch via z-strides.
    gemm_bf16<<<dim3(2, 128, 2), blk, 0, stream>>>(
        x1b, 256, 4194304, w1b, 256, 65536, a1b, 256, 20971520, 256,
        nullptr, nullptr, 0, 1, 0, 1);
    gemm_bf16<<<dim3(2, 128, 1), blk, 0, stream>>>(
        a1b, 256, 0, Dtb, 256, 0, a1db, 256, 0, 256,
        nullptr, nullptr, 0, 0, 0, 1);
    // M GEMM with fused exp + column-sum atomics: Msb = exp((a1d@a2^T)*W)
    gemm_M<<<dim3(4, 4, 32), blk, 0, stream>>>(a1db, a2b, Msb, Wm, Ssum);
    // wih cast (a2b dead) + softmax denominator into x2tb, one dispatch
    post_M<<<dim3(2432), blk, 0, stream>>>(wih, wihb, x2tb, Ssum);
    gemm_bf16<<<dim3(2, 4, 32), blk, 0, stream>>>(
        Msb, 512, 262144, x2tb, 512, 131072, ctxb, 256, 131072, 512,
        nullptr, nullptr, 0, 0, 0, 1);
    // Fused xp = x1b @ wih[:, :256]^T + ctxb @ wih[:, 256:]^T + bih
    gemm_xp<<<dim3(6, 128, 1), blk, 0, stream>>>(x1b, ctxb, wihb, xp, bih);
    gru_kernel<<<dim3(32), dim3(512), 0, stream>>>(xp, whh, bhh, out);
}